// Round 3
// baseline (1306.730 us; speedup 1.0000x reference)
//
#include <hip/hip_runtime.h>
#include <stdint.h>

#define NEDGE 500000
#define NUSR  100000
#define NENT  200000

// ---------------------------------------------------------------------------
// CSR build: histogram -> single-block scan -> cursor scatter.
// ---------------------------------------------------------------------------
__global__ __launch_bounds__(256) void k_hist(
    const int* __restrict__ ui, const int* __restrict__ ii,
    int* __restrict__ deg_u, int* __restrict__ deg_i)
{
  int e = blockIdx.x*256 + threadIdx.x;
  if (e >= NEDGE) return;
  atomicAdd(&deg_u[ui[e]], 1);
  atomicAdd(&deg_i[ii[e]], 1);
}

__device__ void scan_arr(const int* __restrict__ deg, int* __restrict__ off,
                         int n, int* wsum)
{
  const int t = threadIdx.x, lane = t & 63, wv = t >> 6;
  int carry = 0;
  for (int base = 0; base < n; base += 8192){
    int loc[8]; int tsum = 0;
    int i0 = base + t*8;
    #pragma unroll
    for (int j = 0; j < 8; j++){
      int i = i0 + j; int v = (i < n) ? deg[i] : 0;
      loc[j] = tsum; tsum += v;
    }
    int x = tsum;                         // inclusive wave scan
    #pragma unroll
    for (int d = 1; d < 64; d <<= 1){
      int y = __shfl_up(x, d);
      if (lane >= d) x += y;
    }
    if (lane == 63) wsum[wv] = x;
    __syncthreads();
    int wpre = 0, tot = 0;
    #pragma unroll
    for (int w2 = 0; w2 < 16; w2++){
      int s = wsum[w2];
      if (w2 < wv) wpre += s;
      tot += s;
    }
    int tbase = carry + wpre + (x - tsum);
    #pragma unroll
    for (int j = 0; j < 8; j++){
      int i = i0 + j;
      if (i < n) off[i] = tbase + loc[j];
    }
    carry += tot;
    __syncthreads();
  }
  if (t == 0) off[n] = carry;
}

__global__ __launch_bounds__(1024) void k_scan(
    const int* __restrict__ deg_u, int* __restrict__ off_u,
    const int* __restrict__ deg_i, int* __restrict__ off_i)
{
  __shared__ int wsum[16];
  scan_arr(deg_u, off_u, NUSR, wsum);
  __syncthreads();
  scan_arr(deg_i, off_i, NENT, wsum);
}

__global__ __launch_bounds__(256) void k_scatter(
    const int* __restrict__ ui, const int* __restrict__ ii,
    const int* __restrict__ off_u, const int* __restrict__ off_i,
    int* __restrict__ cur_u, int* __restrict__ cur_i,
    int* __restrict__ edge_u, int* __restrict__ edge_i)
{
  int e = blockIdx.x*256 + threadIdx.x;
  if (e >= NEDGE) return;
  int u = ui[e]; int p = atomicAdd(&cur_u[u], 1); edge_u[off_u[u] + p] = e;
  int i = ii[e]; int q = atomicAdd(&cur_i[i], 1); edge_i[off_i[i] + q] = e;
}

// ---------------------------------------------------------------------------
// W transpose prep: Wt[k*64+o] = W[o*128+k]  (k-major so the matvec's scalar
// loads of a k-column are contiguous).
// ---------------------------------------------------------------------------
__global__ __launch_bounds__(256) void k_prep(
    const float* __restrict__ Ww, const float* __restrict__ Wiw,
    float* __restrict__ Wt, float* __restrict__ Wit)
{
  int g = blockIdx.x*256 + threadIdx.x;      // 8192 = 64*128
  int o = g >> 7, k = g & 127;
  Wt [k*64 + o] = Ww [g];
  Wit[k*64 + o] = Wiw[g];
}

// ---------------------------------------------------------------------------
// Per-edge 128->64 matvec, lane=edge, W via wave-uniform scalar loads.
// Block = 128 thr = 2 waves sharing one 64-edge LDS tile; wave w computes
// output slice [32w,32w+32). MODE 0: rel rows + argmax->rtype.
// MODE 1: fused sim_i = dot(rel_iu, y_mean[item]) -- rel never materialized.
// ---------------------------------------------------------------------------
template<int MODE>
__global__ __launch_bounds__(128,2) void k_mv(
    const float* __restrict__ rowsA, const float* __restrict__ rowsB,
    const int* __restrict__ idxA, const int* __restrict__ idxB,
    const float* __restrict__ Wt, const float* __restrict__ Wb,
    const float* __restrict__ lat, const float* __restrict__ ysum,
    float* __restrict__ rel, int* __restrict__ rtype, float* __restrict__ sim)
{
  __shared__ float in_s[64*129];                 // 33 KB, pad 129: 2-way free
  __shared__ float y_s[MODE ? 64*65 : 4];        // MODE1: gathered y rows
  __shared__ int ia_s[64], ib_s[64];
  __shared__ float red_s[2*64*3];                // cross-wave partials

  const int t  = threadIdx.x;
  const int e0 = blockIdx.x * 64;

  if (t < 64){
    int e = e0 + t;
    ia_s[t] = (e < NEDGE) ? idxA[e] : 0;
    ib_s[t] = (e < NEDGE) ? idxB[e] : 0;
  }
  __syncthreads();

  // stage concat rows (+ y rows for MODE1): 16B lane-loads, b32 LDS writes
  const int NITER = MODE ? 24 : 16;
  #pragma unroll
  for (int r = 0; r < NITER; r++){
    int g = t + 128*r;                 // 0..2047 (3071 for MODE1)
    int side = g >> 10;                // 0:A  1:B  2:Y
    int row  = (g >> 4) & 63;
    int c    = g & 15;                 // float4 chunk
    float4 v;
    if (side == 0)      v = *(const float4*)(rowsA + (size_t)ia_s[row]*64 + c*4);
    else if (side == 1) v = *(const float4*)(rowsB + (size_t)ib_s[row]*64 + c*4);
    else                v = *(const float4*)(ysum  + (size_t)ia_s[row]*64 + c*4);
    if (side < 2){
      float* dst = &in_s[row*129 + side*64 + c*4];
      dst[0]=v.x; dst[1]=v.y; dst[2]=v.z; dst[3]=v.w;
    } else {
      float* dst = &y_s[row*65 + c*4];
      dst[0]=v.x; dst[1]=v.y; dst[2]=v.z; dst[3]=v.w;
    }
  }
  __syncthreads();

  const int lane = t & 63;
  const int wv = __builtin_amdgcn_readfirstlane(t >> 6);
  const int ow = wv * 32;
  const float* wp = Wt + ow;                     // wave-uniform -> s_load

  float acc[32];
  #pragma unroll
  for (int o = 0; o < 32; o++) acc[o] = 0.f;

  #pragma unroll 4
  for (int k = 0; k < 128; k++){
    float xv = in_s[lane*129 + k];               // per-lane edge value
    #pragma unroll
    for (int o = 0; o < 32; o++)
      acc[o] = __builtin_fmaf(wp[k*64 + o], xv, acc[o]);
  }
  #pragma unroll
  for (int o = 0; o < 32; o++){
    float v = acc[o] + Wb[ow + o];
    acc[o] = v > 0.f ? v : 0.01f*v;              // leaky_relu(0.01)
  }

  if (MODE == 0){
    // scores vs latent (wave-uniform lat loads), cross-wave reduce via LDS
    #pragma unroll
    for (int f = 0; f < 3; f++){
      float s = 0.f;
      #pragma unroll
      for (int o = 0; o < 32; o++) s += acc[o] * lat[f*64 + ow + o];
      red_s[(f*64 + lane)*2 + wv] = s;
    }
    __syncthreads();                             // also: both waves done with in_s

    // transpose rel to LDS (reuse in_s), then coalesced b32 row stores
    float* rel_s = in_s;
    #pragma unroll
    for (int o = 0; o < 32; o++) rel_s[lane*65 + ow + o] = acc[o];
    __syncthreads();

    if (t < 64 && e0 + t < NEDGE){
      float s0 = red_s[(0*64+t)*2] + red_s[(0*64+t)*2+1];
      float s1 = red_s[(1*64+t)*2] + red_s[(1*64+t)*2+1];
      float s2 = red_s[(2*64+t)*2] + red_s[(2*64+t)*2+1];
      int bf = 0; float bs = s0;
      if (s1 > bs){ bs = s1; bf = 1; }           // strict >: first-max ties
      if (s2 > bs){ bs = s2; bf = 2; }
      rtype[e0 + t] = bf;
    }
    #pragma unroll
    for (int r = 0; r < 32; r++){
      int g = t + 128*r; int e = g >> 6, o = g & 63;
      if (e0 + e < NEDGE)
        rel[(size_t)(e0+e)*64 + o] = rel_s[e*65 + o];
    }
  } else {
    // fused sim_i: dot(rel_iu, y_mean) per edge; y already divided by denom
    float p = 0.f;
    #pragma unroll
    for (int o = 0; o < 32; o++) p += acc[o] * y_s[lane*65 + ow + o];
    red_s[wv*64 + lane] = p;
    __syncthreads();
    if (t < 64 && e0 + t < NEDGE)
      sim[e0 + t] = red_s[t] + red_s[64 + t];
  }
}

// ---------------------------------------------------------------------------
// Entity pre-pass: y_mean[i] = (sum of user rows) / max(deg,1)
// ---------------------------------------------------------------------------
__global__ __launch_bounds__(256) void k_sum_item(
    const float* __restrict__ usr, const int* __restrict__ uidx,
    const int* __restrict__ off_i, const int* __restrict__ edge_i,
    float* __restrict__ ysum)
{
  const int lane = threadIdx.x & 63;
  const int i = blockIdx.x*4 + (threadIdx.x >> 6);
  if (i >= NENT) return;
  const int beg = off_i[i], end = off_i[i+1];
  float s = 0.f;
  for (int k = beg; k < end; k++){
    int e = edge_i[k];
    s += usr[(size_t)uidx[e]*64 + lane];
  }
  ysum[(size_t)i*64 + lane] = s / fmaxf((float)(end - beg), 1.f);
}

// ---------------------------------------------------------------------------
// Entity final: y = (sum sim_i*user_row)/denom -> squash + residual.
// Single gather loop (sim precomputed by fused matvec).
// ---------------------------------------------------------------------------
__global__ __launch_bounds__(256) void k_ent(
    const float* __restrict__ ent, const float* __restrict__ usr,
    const int* __restrict__ uidx, const float* __restrict__ sim,
    const int* __restrict__ off_i, const int* __restrict__ edge_i,
    float* __restrict__ out_ent)
{
  const int lane = threadIdx.x & 63;
  const int i = blockIdx.x*4 + (threadIdx.x >> 6);
  if (i >= NENT) return;
  const int beg = off_i[i], end = off_i[i+1];
  float a = 0.f;
  for (int k = beg; k < end; k++){
    int e = edge_i[k];
    a += sim[e] * usr[(size_t)uidx[e]*64 + lane];
  }
  float v = a / fmaxf((float)(end - beg), 1.f);
  float n2 = v*v;
  #pragma unroll
  for (int m = 1; m < 64; m <<= 1) n2 += __shfl_xor(n2, m);
  float n = sqrtf(n2);
  float fac = (n2/(n2 + 1.f)) / fmaxf(n, 1e-12f);
  out_ent[(size_t)i*64 + lane] = fac*v + ent[(size_t)i*64 + lane];
}

// ---------------------------------------------------------------------------
// User side, one wave per user, LDS row-cache between the two passes.
// ---------------------------------------------------------------------------
#define CAP 24
__global__ __launch_bounds__(256) void k_user(
    const float* __restrict__ ent, const float* __restrict__ usr,
    const float* __restrict__ w3,
    const int* __restrict__ iidx, const int* __restrict__ rtype,
    const float* __restrict__ rel,
    const int* __restrict__ off_u, const int* __restrict__ edge_u,
    float* __restrict__ out_user)
{
  __shared__ float cache[4][CAP][64];
  __shared__ int   ecache[4][CAP];
  __shared__ int   fcc[4][CAP];
  const int lane = threadIdx.x & 63;
  const int wv = threadIdx.x >> 6;
  const int u = blockIdx.x*4 + wv;
  if (u >= NUSR) return;
  const int beg = off_u[u], end = off_u[u+1];

  float s0=0.f, s1=0.f, s2=0.f; int c0=0, c1=0, c2=0;
  for (int k = beg; k < end; k++){
    int j = k - beg;
    int e = edge_u[k];
    int f = rtype[e];
    float row = ent[(size_t)iidx[e]*64 + lane];
    if (j < CAP){
      cache[wv][j][lane] = row;
      if (lane == 0){ ecache[wv][j] = e; fcc[wv][j] = f; }
    }
    if (f == 0){ s0 += row; c0++; }
    else if (f == 1){ s1 += row; c1++; }
    else { s2 += row; c2++; }
  }
  const float d0 = fmaxf((float)c0, 1.f);
  const float d1 = fmaxf((float)c1, 1.f);
  const float d2 = fmaxf((float)c2, 1.f);

  float a0=0.f, a1=0.f, a2=0.f;
  for (int k = beg; k < end; k++){
    int j = k - beg;
    int e, f; float row;
    if (j < CAP){ e = ecache[wv][j]; f = fcc[wv][j]; row = cache[wv][j][lane]; }
    else { e = edge_u[k]; f = rtype[e]; row = ent[(size_t)iidx[e]*64 + lane]; }
    float rv = rel[(size_t)e*64 + lane];
    float ss = (f == 0) ? s0 : ((f == 1) ? s1 : s2);
    float dd = (f == 0) ? d0 : ((f == 1) ? d1 : d2);
    float p = rv * ss;
    #pragma unroll
    for (int m = 1; m < 64; m <<= 1) p += __shfl_xor(p, m);
    float sim = p / dd;
    if (f == 0) a0 += sim*row; else if (f == 1) a1 += sim*row; else a2 += sim*row;
  }

  float wa = w3[0], wb = w3[1], wc = w3[2];
  float mx = fmaxf(wa, fmaxf(wb, wc));
  float ea = expf(wa-mx), eb = expf(wb-mx), ec = expf(wc-mx);
  float inv = 1.f/(ea+eb+ec);
  float ue = usr[(size_t)u*64 + lane];
  float av[3] = {a0,a1,a2}, dv[3] = {d0,d1,d2}, wvv[3] = {ea*inv, eb*inv, ec*inv};
  float o = 0.f;
  #pragma unroll
  for (int f = 0; f < 3; f++){
    float v = av[f]/dv[f];
    float n2 = v*v;
    #pragma unroll
    for (int m = 1; m < 64; m <<= 1) n2 += __shfl_xor(n2, m);
    float n = sqrtf(n2);
    float fac = (n2/(n2 + 1.f)) / fmaxf(n, 1e-12f);
    o += wvv[f]*(fac*v + ue);
  }
  out_user[(size_t)u*64 + lane] = o;
}

// ---------------------------------------------------------------------------
// Workspace (float offsets), ~192 MB total:
//   rel_ui [E*64]  @ 0
//   ysum   [ENT*64]@ 32,000,000
//   sim    [E]     @ 44,800,000
//   Wt     [8192]  @ 45,300,000
//   Wit    [8192]  @ 45,310,000
//   rtype  [E] i32 @ 45,320,000
//   deg_u/cur_u/deg_i/cur_i (zeroed) @ 45,900,000
//   off_u  [U+1]   @ 46,500,000
//   off_i  [ENT+1] @ 46,700,000
//   edge_u [E]     @ 47,000,000
//   edge_i [E]     @ 47,500,000
// ---------------------------------------------------------------------------
extern "C" void kernel_launch(void* const* d_in, const int* in_sizes, int n_in,
                              void* d_out, int out_size, void* d_ws, size_t ws_size,
                              hipStream_t stream) {
  const float* ent = (const float*)d_in[0];
  const float* usr = (const float*)d_in[1];
  const float* lat = (const float*)d_in[2];
  const int*   ui  = (const int*)d_in[3];
  const int*   ii  = (const int*)d_in[4];
  const float* Ww  = (const float*)d_in[5];
  const float* Wb  = (const float*)d_in[6];
  const float* Wiw = (const float*)d_in[7];
  const float* Wib = (const float*)d_in[8];
  const float* w3  = (const float*)d_in[9];

  float* ws = (float*)d_ws;
  float* rel_ui = ws;
  float* ysum   = ws + 32000000ull;
  float* sim    = ws + 44800000ull;
  float* Wt     = ws + 45300000ull;
  float* Wit    = ws + 45310000ull;
  int*   rtype  = (int*)(ws + 45320000ull);
  int*   deg_u  = (int*)(ws + 45900000ull);
  int*   cur_u  = deg_u + 100000;
  int*   deg_i  = cur_u + 100000;
  int*   cur_i  = deg_i + 200000;
  int*   off_u  = (int*)(ws + 46500000ull);
  int*   off_i  = (int*)(ws + 46700000ull);
  int*   edge_u = (int*)(ws + 47000000ull);
  int*   edge_i = (int*)(ws + 47500000ull);

  float* out_ent  = (float*)d_out;
  float* out_user = (float*)d_out + (size_t)NENT*64;

  hipMemsetAsync(deg_u, 0, 600000*sizeof(int), stream);

  k_hist<<<1954, 256, 0, stream>>>(ui, ii, deg_u, deg_i);
  k_scan<<<1, 1024, 0, stream>>>(deg_u, off_u, deg_i, off_i);
  k_scatter<<<1954, 256, 0, stream>>>(ui, ii, off_u, off_i,
                                      cur_u, cur_i, edge_u, edge_i);
  k_prep<<<32, 256, 0, stream>>>(Ww, Wiw, Wt, Wit);

  // relation_ui = leaky(concat([user,item]) @ Ww^T + b) -> rel rows + rtype
  k_mv<0><<<7813, 128, 0, stream>>>(usr, ent, ui, ii, Wt, Wb, lat,
                                    (const float*)nullptr, rel_ui, rtype, sim);
  // y_mean per entity (no argmax dependency)
  k_sum_item<<<50000, 256, 0, stream>>>(usr, ui, off_i, edge_i, ysum);
  // relation_iu fused with sim_i (rel_iu never materialized)
  k_mv<1><<<7813, 128, 0, stream>>>(ent, usr, ii, ui, Wit, Wib, lat,
                                    ysum, rel_ui /*unused*/, rtype /*unused*/, sim);

  k_user<<<25000, 256, 0, stream>>>(ent, usr, w3, ii, rtype, rel_ui,
                                    off_u, edge_u, out_user);
  k_ent<<<50000, 256, 0, stream>>>(ent, usr, ui, sim,
                                   off_i, edge_i, out_ent);
}